// Round 6
// baseline (1897.130 us; speedup 1.0000x reference)
//
#include <hip/hip_runtime.h>
#include <stdint.h>

#define NN 384
#define NE 3456
#define NLb 32
#define F 64
#define KD 32

typedef short shortx8 __attribute__((ext_vector_type(8)));
typedef float floatx4 __attribute__((ext_vector_type(4)));

__device__ __forceinline__ float sigm(float v) { return 1.0f / (1.0f + __expf(-v)); }
__device__ __forceinline__ float tanhf_(float v) {
    float x = fminf(fmaxf(v, -15.0f), 15.0f);
    float e = __expf(2.0f * x);
    return (e - 1.0f) / (e + 1.0f);
}
__device__ __forceinline__ uint16_t f2bf(float f) {
    uint32_t u = __float_as_uint(f);
    uint32_t r = (u + 0x7fffu + ((u >> 16) & 1u)) >> 16;
    return (uint16_t)r;
}
__device__ __forceinline__ float bf2f(uint16_t h) {
    return __uint_as_float((uint32_t)h << 16);
}

__global__ void k_zero(float* p, int n) {
    int i = blockIdx.x * 256 + threadIdx.x;
    int st = gridDim.x * 256;
    for (; i < n; i += st) p[i] = 0.0f;
}

__global__ void k_build(const int* __restrict__ e1, const int* __restrict__ e2,
                        float* __restrict__ C, float* __restrict__ Adj) {
    int t = blockIdx.x * 256 + threadIdx.x;
    if (t >= 2 * NE) return;
    int g = t / NE, e = t % NE;
    const int* ei = g ? e2 : e1;
    int s = ei[e], d = ei[NE + e];
    atomicAdd(&C[(size_t)g * NN * NN + d * NN + s], 1.0f);
    if (e < NE - NN) Adj[(size_t)g * NN * NN + s * NN + d] = 1.0f;
}

__global__ void k_degx(const float* __restrict__ f1, const float* __restrict__ f2,
                       const float* __restrict__ Adj, float* __restrict__ X) {
    int g = blockIdx.y;
    int s = blockIdx.x * 64 + threadIdx.x;
    const float* feats = g ? f2 : f1;
    const float* A = Adj + (size_t)g * NN * NN;
    float* Xg = X + (size_t)g * NN * 33;
    float deg = 0.0f;
    for (int d = 0; d < NN; d++) deg += A[s * NN + d];
    for (int c = 0; c < NLb; c++) Xg[s * 33 + c] = feats[s * NLb + c];
    Xg[s * 33 + 32] = deg;
}

__global__ __launch_bounds__(64)
void k_lin0(const float* __restrict__ X, const float* __restrict__ w1,
            const float* __restrict__ b1, const float* __restrict__ w2,
            const float* __restrict__ b2, float* __restrict__ HS) {
    __shared__ float tl[64];
    int g = blockIdx.y, m = blockIdx.x, n = threadIdx.x;
    const float* Xr = X + (size_t)g * NN * 33 + m * 33;
    float t = b1[n];
#pragma unroll
    for (int k = 0; k < 33; k++) t += Xr[k] * w1[k * F + n];
    t = fmaxf(t, 0.0f);
    tl[n] = t;
    __syncthreads();
    float o = b2[n];
#pragma unroll 4
    for (int k = 0; k < F; k++) o += tl[k] * w2[k * F + n];
    HS[(size_t)g * (6 * NN * F) + m * F + n] = o;
}

__global__ __launch_bounds__(64)
void k_gin(const float* __restrict__ C, const float* __restrict__ hin, int hGs,
           const float* __restrict__ gw1, const float* __restrict__ gb1,
           const float* __restrict__ gw2, const float* __restrict__ gb2,
           const float* __restrict__ geps, int li,
           float* __restrict__ zout, int oGs) {
    __shared__ float zl[64], tl[64];
    int g = blockIdx.y, m = blockIdx.x, n = threadIdx.x;
    const float* Crow = C + (size_t)g * NN * NN + (size_t)m * NN;
    const float* h = hin + (size_t)g * hGs;
    float acc = 0.0f;
#pragma unroll 4
    for (int k = 0; k < NN; k++) acc += Crow[k] * h[k * F + n];
    acc += (1.0f + geps[li]) * h[m * F + n];
    zl[n] = acc;
    __syncthreads();
    const float* W1 = gw1 + (size_t)li * F * F;
    const float* W2 = gw2 + (size_t)li * F * F;
    float t = gb1[li * F + n];
#pragma unroll 4
    for (int k = 0; k < F; k++) t += zl[k] * W1[k * F + n];
    t = fmaxf(t, 0.0f);
    tl[n] = t;
    __syncthreads();
    float o = gb2[li * F + n];
#pragma unroll 4
    for (int k = 0; k < F; k++) o += tl[k] * W2[k * F + n];
    zout[(size_t)g * oGs + m * F + n] = o;
}

__global__ __launch_bounds__(256)
void k_bn(float* __restrict__ hsb, int hsGs, float* __restrict__ hbuf, int hGs,
          const float* __restrict__ gamma, const float* __restrict__ beta) {
    __shared__ float red[4][64];
    int g = blockIdx.x;
    float* z = hsb + (size_t)g * hsGs;
    float* h = hbuf + (size_t)g * hGs;
    int c = threadIdx.x & 63, rq = threadIdx.x >> 6;
    int r0 = rq * 96;
    float s = 0.0f;
    for (int r = r0; r < r0 + 96; r++) s += z[r * F + c];
    red[rq][c] = s;
    __syncthreads();
    float mu = (red[0][c] + red[1][c] + red[2][c] + red[3][c]) * (1.0f / NN);
    __syncthreads();
    float v = 0.0f;
    for (int r = r0; r < r0 + 96; r++) { float d = z[r * F + c] - mu; v += d * d; }
    red[rq][c] = v;
    __syncthreads();
    float var = (red[0][c] + red[1][c] + red[2][c] + red[3][c]) * (1.0f / NN);
    float is = rsqrtf(var + 1e-5f);
    float ga = gamma[c], be = beta[c];
    for (int r = r0; r < r0 + 96; r++) {
        float zn = (z[r * F + c] - mu) * is * ga + be;
        z[r * F + c] = zn;
        h[r * F + c] = fmaxf(zn, 0.0f);
    }
}

// f32 HS (graph 1 only) -> bf16 hi/lo
__global__ void k_cvt2(const float* __restrict__ HS, uint16_t* __restrict__ hhi,
                       uint16_t* __restrict__ hlo) {
    int idx = blockIdx.x * 256 + threadIdx.x;
    if (idx >= 6 * NN * F) return;
    float v = HS[idx];
    uint16_t h = f2bf(v);
    hhi[idx] = h;
    hlo[idx] = f2bf(v - bf2f(h));
}

__global__ __launch_bounds__(64)
void k_gedT2(const float* __restrict__ ged, uint16_t* __restrict__ ghi,
             uint16_t* __restrict__ glo) {
    __shared__ float t[64 * 65];
    int lk = blockIdx.x, lane = threadIdx.x;
    const float* src = ged + (size_t)lk * 4096;
    for (int d = 0; d < 64; d++) t[lane * 65 + d] = src[d * 64 + lane];
    __syncthreads();
    for (int e = 0; e < 64; e++) {
        float v = t[e * 65 + lane];
        uint16_t h = f2bf(v);
        ghi[(size_t)lk * 4096 + e * 64 + lane] = h;
        glo[(size_t)lk * 4096 + e * 64 + lane] = f2bf(v - bf2f(h));
    }
}

// wpack (f32):
// [0    wih 3072][3072 whh 3072][6144 wawT 1024][7168 vwT 1024]
// [8192 bRZ 64 (bih+bhh rows 0..63)][8256 biN 32][8288 bhN 32]
// [8320 wab 32][8352 vat 32][8384 vb 32]   total 8416
__global__ __launch_bounds__(256)
void k_wprep4(const float* __restrict__ wih, const float* __restrict__ whh,
              const float* __restrict__ waw, const float* __restrict__ vw,
              const float* __restrict__ bih, const float* __restrict__ bhh,
              const float* __restrict__ wab, const float* __restrict__ vat,
              const float* __restrict__ vb, float* __restrict__ wp) {
    int t = threadIdx.x;
    for (int idx = t; idx < 3072; idx += 256) {
        wp[idx] = wih[idx];
        wp[3072 + idx] = whh[idx];
    }
    for (int idx = t; idx < 1024; idx += 256) {
        int c = idx >> 5, k = idx & 31;
        wp[6144 + idx] = waw[k * 32 + c];
        wp[7168 + idx] = vw[k * 32 + c];
    }
    if (t < 64) wp[8192 + t] = bih[t] + bhh[t];
    if (t < 32) {
        wp[8256 + t] = bih[64 + t];
        wp[8288 + t] = bhh[64 + t];
        wp[8320 + t] = wab[t];
        wp[8352 + t] = vat[t];
        wp[8384 + t] = vb[t];
    }
}

// T1f[l,i,n=k*64+e] = sum_d gedT[l,n,d]*h1[l,i,d]  (hi/lo MFMA, f32 out)
__global__ __launch_bounds__(256)
void k_t1m2(const uint16_t* __restrict__ gThi, const uint16_t* __restrict__ gTlo,
            const uint16_t* __restrict__ hbhi, const uint16_t* __restrict__ hblo,
            float* __restrict__ T1f) {
    int l = blockIdx.z;
    int w = threadIdx.x >> 6, lane = threadIdx.x & 63;
    int nb = blockIdx.x * 128 + (w >> 1) * 64;
    int ib = blockIdx.y * 128 + (w & 1) * 64;
    int lr = lane & 15, lq = lane >> 4;
    const uint16_t* gah = gThi + (size_t)l * 2048 * 64;
    const uint16_t* gal = gTlo + (size_t)l * 2048 * 64;
    const uint16_t* gbh = hbhi + (size_t)l * NN * F;
    const uint16_t* gbl = hblo + (size_t)l * NN * F;
    shortx8 Ah[4][2], Al[4][2];
#pragma unroll
    for (int s = 0; s < 4; s++)
#pragma unroll
        for (int ks = 0; ks < 2; ks++) {
            size_t off = (size_t)(nb + s * 16 + lr) * 64 + ks * 32 + lq * 8;
            Ah[s][ks] = *reinterpret_cast<const shortx8*>(gah + off);
            Al[s][ks] = *reinterpret_cast<const shortx8*>(gal + off);
        }
#pragma unroll
    for (int si = 0; si < 4; si++) {
        shortx8 Bh[2], Bl[2];
#pragma unroll
        for (int ks = 0; ks < 2; ks++) {
            size_t off = (size_t)(ib + si * 16 + lr) * 64 + ks * 32 + lq * 8;
            Bh[ks] = *reinterpret_cast<const shortx8*>(gbh + off);
            Bl[ks] = *reinterpret_cast<const shortx8*>(gbl + off);
        }
#pragma unroll
        for (int sn = 0; sn < 4; sn++) {
            floatx4 a = (floatx4){0.f, 0.f, 0.f, 0.f};
#pragma unroll
            for (int ks = 0; ks < 2; ks++) {
                a = __builtin_amdgcn_mfma_f32_16x16x32_bf16(Ah[sn][ks], Bh[ks], a, 0, 0, 0);
                a = __builtin_amdgcn_mfma_f32_16x16x32_bf16(Ah[sn][ks], Bl[ks], a, 0, 0, 0);
                a = __builtin_amdgcn_mfma_f32_16x16x32_bf16(Al[sn][ks], Bh[ks], a, 0, 0, 0);
            }
            size_t addr = ((size_t)l * NN + (ib + si * 16 + lr)) * 2048 + (nb + sn * 16 + lq * 4);
            *reinterpret_cast<floatx4*>(T1f + addr) = a;
        }
    }
}

#define DOT4(W, A, B4) ((A)[4*(B4)+0]*(W).x + (A)[4*(B4)+1]*(W).y + \
                        (A)[4*(B4)+2]*(W).z + (A)[4*(B4)+3]*(W).w)

// Block = 192 threads, grid (NN): i = blockIdx.x. Each thread owns 2 pairs:
// jA = TX, jB = TX+192. All loop-resident weights + T1 tile in LDS, read as
// b128 broadcast; every b128 read feeds 8 FMAs (4 components x 2 pairs).
__global__ __launch_bounds__(192, 1)
void k_mega7(const float* __restrict__ T1f, const float* __restrict__ HS2,
             const float* __restrict__ wpack,
             const float* __restrict__ q1w, const float* __restrict__ q1b,
             const float* __restrict__ q2w, const float* __restrict__ q2b,
             const float* __restrict__ kw, const float* __restrict__ kb,
             float* __restrict__ out) {
    __shared__ float wl[8416];
    __shared__ float t1l[2048];
    __shared__ float hl[192 * 66];
    const int i = blockIdx.x;
    const int TX = threadIdx.x;
    const int jA = TX, jB = TX + 192;

    for (int idx = TX; idx < 8416; idx += 192) wl[idx] = wpack[idx];
#pragma unroll
    for (int k = 0; k < KD; k++) { hl[TX * 66 + k] = 0.0f; hl[TX * 66 + 33 + k] = 0.0f; }

    float hA[KD], hB[KD], pA[KD], pB[KD];
#pragma unroll
    for (int k = 0; k < KD; k++) { hA[k] = 0.0f; hB[k] = 0.0f; pA[k] = 0.0f; pB[k] = 0.0f; }
    float smA = -1e30f, sdA = 0.0f, smB = -1e30f, sdB = 0.0f;

#define FILL_T1(LL) do {                                                       \
    __syncthreads();                                                           \
    const float4* srcp = reinterpret_cast<const float4*>(                      \
        T1f + ((size_t)(LL) * NN + i) * 2048);                                 \
    for (int idx = TX; idx < 512; idx += 192)                                  \
        reinterpret_cast<float4*>(t1l)[idx] = srcp[idx];                       \
    __syncthreads();                                                           \
} while (0)

#define COMPUTE_X2(LL) do {                                                    \
    _Pragma("unroll") for (int k = 0; k < KD; k++) { xA[k] = 0.0f; xB[k] = 0.0f; } \
    const float4* hAp = reinterpret_cast<const float4*>(                       \
        HS2 + ((size_t)(LL) * NN + jA) * 64);                                  \
    const float4* hBp = reinterpret_cast<const float4*>(                       \
        HS2 + ((size_t)(LL) * NN + jB) * 64);                                  \
    _Pragma("unroll 2")                                                        \
    for (int eb = 0; eb < 16; eb++) {                                          \
        float4 a4 = hAp[eb], b4 = hBp[eb];                                     \
        _Pragma("unroll") for (int k = 0; k < KD; k++) {                       \
            floatx4 t4 = *reinterpret_cast<const floatx4*>(t1l + k * 64 + eb * 4); \
            xA[k] += t4[0]*a4.x + t4[1]*a4.y + t4[2]*a4.z + t4[3]*a4.w;        \
            xB[k] += t4[0]*b4.x + t4[1]*b4.y + t4[2]*b4.z + t4[3]*b4.w;        \
        }                                                                      \
    }                                                                          \
} while (0)

    // ================= phase A: GRU + layer attention =================
#pragma unroll 1
    for (int l = 0; l < 6; l++) {
        FILL_T1(l);
        float xA[KD], xB[KD];
        COMPUTE_X2(l);
#pragma unroll 2
        for (int g = 0; g < KD; g++) {
            const floatx4* wiR = reinterpret_cast<const floatx4*>(wl + g * 32);
            const floatx4* wiZ = reinterpret_cast<const floatx4*>(wl + 1024 + g * 32);
            const floatx4* wiN = reinterpret_cast<const floatx4*>(wl + 2048 + g * 32);
            const floatx4* whR = reinterpret_cast<const floatx4*>(wl + 3072 + g * 32);
            const floatx4* whZ = reinterpret_cast<const floatx4*>(wl + 4096 + g * 32);
            const floatx4* whN = reinterpret_cast<const floatx4*>(wl + 5120 + g * 32);
            float irA = 0, izA = 0, inA = 0, hrA = 0, hzA = 0, hnA = 0;
            float irB = 0, izB = 0, inB = 0, hrB = 0, hzB = 0, hnB = 0;
#pragma unroll
            for (int k4 = 0; k4 < 8; k4++) {
                floatx4 w;
                w = wiR[k4]; irA += DOT4(w, xA, k4); irB += DOT4(w, xB, k4);
                w = wiZ[k4]; izA += DOT4(w, xA, k4); izB += DOT4(w, xB, k4);
                w = wiN[k4]; inA += DOT4(w, xA, k4); inB += DOT4(w, xB, k4);
                w = whR[k4]; hrA += DOT4(w, hA, k4); hrB += DOT4(w, hB, k4);
                w = whZ[k4]; hzA += DOT4(w, hA, k4); hzB += DOT4(w, hB, k4);
                w = whN[k4]; hnA += DOT4(w, hA, k4); hnB += DOT4(w, hB, k4);
            }
            float bR = wl[8192 + g], bZ = wl[8224 + g];
            float biN = wl[8256 + g], bhN = wl[8288 + g];
            float rA = sigm(irA + hrA + bR);
            float zA = sigm(izA + hzA + bZ);
            float nA = tanhf_(inA + biN + rA * (hnA + bhN));
            float rB = sigm(irB + hrB + bR);
            float zB = sigm(izB + hzB + bZ);
            float nB = tanhf_(inB + biN + rB * (hnB + bhN));
            float oldA = hl[TX * 66 + g], oldB = hl[TX * 66 + 33 + g];
            hl[TX * 66 + g]      = (1.0f - zA) * nA + zA * oldA;
            hl[TX * 66 + 33 + g] = (1.0f - zB) * nB + zB * oldB;
        }
#pragma unroll
        for (int k = 0; k < KD; k++) {
            hA[k] = hl[TX * 66 + k];
            hB[k] = hl[TX * 66 + 33 + k];
        }
        // attention score
        float scA = 0.0f, scB = 0.0f;
#pragma unroll 2
        for (int c = 0; c < KD; c++) {
            const floatx4* wr = reinterpret_cast<const floatx4*>(wl + 6144 + c * 32);
            float tA = wl[8320 + c], tB = tA;
#pragma unroll
            for (int k4 = 0; k4 < 8; k4++) {
                floatx4 w = wr[k4];
                tA += DOT4(w, hA, k4);
                tB += DOT4(w, hB, k4);
            }
            float va = wl[8352 + c];
            scA += tanhf_(tA) * va;
            scB += tanhf_(tB) * va;
        }
        float nmA = fmaxf(smA, scA);
        float eoA = __expf(smA - nmA), enA = __expf(scA - nmA);
        sdA = sdA * eoA + enA; smA = nmA;
        float nmB = fmaxf(smB, scB);
        float eoB = __expf(smB - nmB), enB = __expf(scB - nmB);
        sdB = sdB * eoB + enB; smB = nmB;
#pragma unroll
        for (int k = 0; k < KD; k++) {
            pA[k] = pA[k] * eoA + enA * hA[k];
            pB[k] = pB[k] * eoB + enB * hB[k];
        }
    }

    // ---------------- per-thread: pattern -> q -> qk (per pair) ----------------
    float qkA[KD], qkB[KD], qdA, qdB;
    {
        float invA = 1.0f / sdA, invB = 1.0f / sdB;
#pragma unroll
        for (int k = 0; k < KD; k++) { pA[k] *= invA; pB[k] *= invB; }
        float t1rA[KD], t1rB[KD];
#pragma unroll
        for (int c = 0; c < KD; c++) {
            float tA = q1b[c], tB = tA;
#pragma unroll
            for (int k = 0; k < KD; k++) {
                float w = q1w[k * KD + c];
                tA += pA[k] * w; tB += pB[k] * w;
            }
            t1rA[c] = fmaxf(tA, 0.0f); t1rB[c] = fmaxf(tB, 0.0f);
        }
        float qA[KD], qB[KD];
#pragma unroll
        for (int c = 0; c < KD; c++) {
            float tA = q2b[c], tB = tA;
#pragma unroll
            for (int k = 0; k < KD; k++) {
                float w = q2w[k * KD + c];
                tA += t1rA[k] * w; tB += t1rB[k] * w;
            }
            qA[c] = tA; qB[c] = tB;
        }
        qdA = 0.0f; qdB = 0.0f;
#pragma unroll
        for (int c = 0; c < KD; c++) { qdA += qA[c] * kb[c]; qdB += qB[c] * kb[c]; }
#pragma unroll
        for (int k = 0; k < KD; k++) {
            float tA = 0.0f, tB = 0.0f;
#pragma unroll
            for (int c = 0; c < KD; c++) {
                float w = kw[k * KD + c];
                tA += qA[c] * w; tB += qB[c] * w;
            }
            qkA[k] = tA; qkB[k] = tB;
        }
    }

    // ================= phase B: scores + context =================
    float cA[KD], cB[KD];
#pragma unroll
    for (int k = 0; k < KD; k++) { cA[k] = 0.0f; cB[k] = 0.0f; }
    float s2mA = -1e30f, s2dA = 0.0f, s2mB = -1e30f, s2dB = 0.0f;
#pragma unroll 1
    for (int l = 0; l < 6; l++) {
        FILL_T1(l);
        float xA[KD], xB[KD];
        COMPUTE_X2(l);
        float sA = qdA, sB = qdB;
#pragma unroll
        for (int k = 0; k < KD; k++) { sA += xA[k] * qkA[k]; sB += xB[k] * qkB[k]; }
        sA *= 0.17677669529663687f; sB *= 0.17677669529663687f;
        float nmA = fmaxf(s2mA, sA);
        float eoA = __expf(s2mA - nmA), enA = __expf(sA - nmA);
        s2dA = s2dA * eoA + enA; s2mA = nmA;
        float nmB = fmaxf(s2mB, sB);
        float eoB = __expf(s2mB - nmB), enB = __expf(sB - nmB);
        s2dB = s2dB * eoB + enB; s2mB = nmB;
#pragma unroll 2
        for (int c = 0; c < KD; c++) {
            const floatx4* vr = reinterpret_cast<const floatx4*>(wl + 7168 + c * 32);
            float vA = wl[8384 + c], vB = vA;
#pragma unroll
            for (int k4 = 0; k4 < 8; k4++) {
                floatx4 w = vr[k4];
                vA += DOT4(w, xA, k4);
                vB += DOT4(w, xB, k4);
            }
            cA[c] = cA[c] * eoA + enA * vA;
            cB[c] = cB[c] * eoB + enB * vB;
        }
    }
    float invdA = 1.0f / s2dA, invdB = 1.0f / s2dB;
    float* opA = out + ((size_t)i * NN + jA) * KD;
    float* opB = out + ((size_t)i * NN + jB) * KD;
#pragma unroll
    for (int k = 0; k < KD; k += 4) {
        float4 w4;
        w4.x = cA[k] * invdA; w4.y = cA[k + 1] * invdA;
        w4.z = cA[k + 2] * invdA; w4.w = cA[k + 3] * invdA;
        *reinterpret_cast<float4*>(opA + k) = w4;
        w4.x = cB[k] * invdB; w4.y = cB[k + 1] * invdB;
        w4.z = cB[k + 2] * invdB; w4.w = cB[k + 3] * invdB;
        *reinterpret_cast<float4*>(opB + k) = w4;
    }
#undef FILL_T1
#undef COMPUTE_X2
}

extern "C" void kernel_launch(void* const* d_in, const int* in_sizes, int n_in,
                              void* d_out, int out_size, void* d_ws, size_t ws_size,
                              hipStream_t stream) {
    const float* f1   = (const float*)d_in[0];
    const float* f2   = (const float*)d_in[1];
    const float* l0w1 = (const float*)d_in[2];
    const float* l0b1 = (const float*)d_in[3];
    const float* l0w2 = (const float*)d_in[4];
    const float* l0b2 = (const float*)d_in[5];
    const float* geps = (const float*)d_in[6];
    const float* gw1  = (const float*)d_in[7];
    const float* gb1  = (const float*)d_in[8];
    const float* gw2  = (const float*)d_in[9];
    const float* gb2  = (const float*)d_in[10];
    const float* gga  = (const float*)d_in[11];
    const float* gbe  = (const float*)d_in[12];
    const float* ged  = (const float*)d_in[13];
    const float* wih  = (const float*)d_in[14];
    const float* whh  = (const float*)d_in[15];
    const float* bih  = (const float*)d_in[16];
    const float* bhh  = (const float*)d_in[17];
    const float* waw  = (const float*)d_in[18];
    const float* wab  = (const float*)d_in[19];
    const float* vat  = (const float*)d_in[20];
    const float* q1w  = (const float*)d_in[21];
    const float* q1b  = (const float*)d_in[22];
    const float* q2w  = (const float*)d_in[23];
    const float* q2b  = (const float*)d_in[24];
    const float* kw   = (const float*)d_in[25];
    const float* kb   = (const float*)d_in[26];
    const float* vw   = (const float*)d_in[27];
    const float* vb   = (const float*)d_in[28];
    const int*   e1   = (const int*)d_in[29];
    const int*   e2   = (const int*)d_in[30];

    // ---- workspace layout ----
    float* C     = (float*)d_ws;                        // 2*NN*NN
    float* Adj   = C + (size_t)2 * NN * NN;
    float* X     = Adj + (size_t)2 * NN * NN;           // 2*NN*33
    float* H     = X + (size_t)2 * NN * 33;             // 2*NN*F
    float* HS    = H + (size_t)2 * NN * F;              // [2][6][NN][F]
    float* T1f   = HS + (size_t)2 * 6 * NN * F;         // 6*NN*2048
    float* wpack = T1f + (size_t)6 * NN * 2048;         // 8416
    uint16_t* hbhi = (uint16_t*)(wpack + 8448);         // 6*NN*F
    uint16_t* hblo = hbhi + (size_t)6 * NN * F;
    uint16_t* gThi = hblo + (size_t)6 * NN * F;         // 6*2048*64
    uint16_t* gTlo = gThi + (size_t)6 * 2048 * 64;
    float* out = (float*)d_out;

    const int GHS = 6 * NN * F;
    const int GH  = NN * F;

    k_zero<<<576, 256, 0, stream>>>(C, 4 * NN * NN);
    k_build<<<(2 * NE + 255) / 256, 256, 0, stream>>>(e1, e2, C, Adj);
    k_degx<<<dim3(6, 2), 64, 0, stream>>>(f1, f2, Adj, X);
    k_lin0<<<dim3(NN, 2), 64, 0, stream>>>(X, l0w1, l0b1, l0w2, l0b2, HS);
    for (int li = 0; li < 5; li++) {
        const float* hp = (li == 0) ? HS : H;
        int hGs = (li == 0) ? GHS : GH;
        k_gin<<<dim3(NN, 2), 64, 0, stream>>>(C, hp, hGs, gw1, gb1, gw2, gb2,
                                              geps, li, HS + (li + 1) * GH, GHS);
        k_bn<<<2, 256, 0, stream>>>(HS + (li + 1) * GH, GHS, H, GH,
                                    gga + li * F, gbe + li * F);
    }
    k_cvt2<<<(6 * NN * F + 255) / 256, 256, 0, stream>>>(HS, hbhi, hblo);
    k_gedT2<<<6 * KD, 64, 0, stream>>>(ged, gThi, gTlo);
    k_wprep4<<<1, 256, 0, stream>>>(wih, whh, waw, vw, bih, bhh, wab, vat, vb, wpack);
    k_t1m2<<<dim3(16, 3, 6), 256, 0, stream>>>(gThi, gTlo, hbhi, hblo, T1f);
    k_mega7<<<dim3(NN), 192, 0, stream>>>(T1f, HS + GHS, wpack,
                                          q1w, q1b, q2w, q2b, kw, kb, out);
}